// Round 10
// baseline (496.182 us; speedup 1.0000x reference)
//
#include <hip/hip_runtime.h>

#define N_NODES 50000
#define N_EDGES 600000
#define HIDDEN 128
#define N_GRAPHS 64
#define SLICES 16
#define SCAN_B ((N_NODES + 255) / 256)   // 196
#define NG32 ((N_NODES + 31) / 32)       // 1563 node-groups of 32

// Feature-chunked layout for all node matrices: elem(n,f) at
// ((f>>4) * N_NODES + n) * 16 + (f & 15).  Chunk = 3.2 MB -> fits XCD L2.

// ---------------- degree ----------------

__global__ void deg_kernel(const int* __restrict__ dst, int* __restrict__ deg) {
    int t = blockIdx.x * 256 + threadIdx.x;
    if (t < N_EDGES) atomicAdd(&deg[dst[t]], 1);
}

// ---------------- 3-pass parallel scan: deg -> rowptr (+ fused dinv) ----------------

__global__ void scan_partial(const int* __restrict__ deg, int* __restrict__ bsum) {
    const int b = blockIdx.x, t = threadIdx.x;
    const int i = b * 256 + t;
    int v = (i < N_NODES) ? deg[i] : 0;
    __shared__ int wsum[4];
#pragma unroll
    for (int o = 32; o > 0; o >>= 1) v += __shfl_down(v, o, 64);
    if ((t & 63) == 0) wsum[t >> 6] = v;
    __syncthreads();
    if (t == 0) bsum[b] = wsum[0] + wsum[1] + wsum[2] + wsum[3];
}

__global__ void scan_bsum(const int* __restrict__ bsum, int* __restrict__ boff,
                          int* __restrict__ rowptr) {
    __shared__ int s[256];
    const int t = threadIdx.x;
    const int v = (t < SCAN_B) ? bsum[t] : 0;
    s[t] = v;
    __syncthreads();
    for (int o = 1; o < 256; o <<= 1) {
        int u = (t >= o) ? s[t - o] : 0;
        __syncthreads();
        s[t] += u;
        __syncthreads();
    }
    if (t < SCAN_B) boff[t] = s[t] - v;      // exclusive
    if (t == 255) rowptr[N_NODES] = s[255];  // total == N_EDGES
}

__global__ void scan_final(const int* __restrict__ deg, const int* __restrict__ boff,
                           int* __restrict__ rowptr, float* __restrict__ dinv) {
    const int b = blockIdx.x, t = threadIdx.x;
    const int i = b * 256 + t;
    __shared__ int s[256];
    const int v = (i < N_NODES) ? deg[i] : 0;
    s[t] = v;
    __syncthreads();
    for (int o = 1; o < 256; o <<= 1) {
        int u = (t >= o) ? s[t - o] : 0;
        __syncthreads();
        s[t] += u;
        __syncthreads();
    }
    if (i < N_NODES) {
        rowptr[i] = boff[b] + s[t] - v;
        dinv[i] = rsqrtf((float)v + 1.0f);
    }
}

// ---------------- CSR fill (src only; norm recomputed in gather) ----------------

__global__ void fill_kernel(const int* __restrict__ src, const int* __restrict__ dst,
                            const int* __restrict__ rowptr, int* __restrict__ fillcnt,
                            int* __restrict__ csr_src) {
    int e = blockIdx.x * 256 + threadIdx.x;
    if (e >= N_EDGES) return;
    const int d = dst[e];
    const int pos = rowptr[d] + atomicAdd(&fillcnt[d], 1);
    csr_src[pos] = src[e];
}

// ---------------- GEMM: C_chunked[N x 128] = A @ W ----------------
// CHA: A feature-chunked; else row-major. C always chunked.
// Staging + epilogue use idx->(node,c,f4) mapping: LDS consecutive (no bank
// conflicts), global 128B-contiguous per chunk per wave.

template <bool CHA, bool BIAS>
__global__ void gemm_kernel(const float* __restrict__ A, const float* __restrict__ W,
                            float* __restrict__ C, const float* __restrict__ bias,
                            int nrows) {
    __shared__ float As[64 * 128];
    const int r0 = blockIdx.x * 64;
    const int tid = threadIdx.x;
    float4* As4 = reinterpret_cast<float4*>(As);

    if (CHA) {
        const float4* Ag = reinterpret_cast<const float4*>(A);
#pragma unroll
        for (int i = 0; i < 8; i++) {
            const int idx = tid + i * 256;       // 0..2047
            const int node = idx >> 5;           // 0..63
            const int c = (idx >> 2) & 7;        // chunk
            const int f4 = idx & 3;
            float4 v = make_float4(0.f, 0.f, 0.f, 0.f);
            if (r0 + node < nrows) v = Ag[((long)c * N_NODES + r0 + node) * 4 + f4];
            As4[idx] = v;                        // row-major [node][feature]
        }
    } else {
        const float4* Ag = reinterpret_cast<const float4*>(A + (long)r0 * HIDDEN);
        const int maxv = (nrows - r0) * (HIDDEN / 4);
#pragma unroll
        for (int i = 0; i < 8; i++) {
            int idx = tid + i * 256;
            float4 v = make_float4(0.f, 0.f, 0.f, 0.f);
            if (idx < maxv) v = Ag[idx];
            As4[idx] = v;
        }
    }
    __syncthreads();

    const int tx = tid & 31;
    const int ty = tid >> 5;

    float acc[8][4];
#pragma unroll
    for (int r = 0; r < 8; r++)
#pragma unroll
        for (int c = 0; c < 4; c++) acc[r][c] = 0.f;

    const float4* Wg = reinterpret_cast<const float4*>(W);
    for (int k4 = 0; k4 < 32; k4++) {
        const float4 w0 = Wg[(4 * k4 + 0) * 32 + tx];
        const float4 w1 = Wg[(4 * k4 + 1) * 32 + tx];
        const float4 w2 = Wg[(4 * k4 + 2) * 32 + tx];
        const float4 w3 = Wg[(4 * k4 + 3) * 32 + tx];
#pragma unroll
        for (int r = 0; r < 8; r++) {
            const float4 a = *reinterpret_cast<const float4*>(&As[(ty * 8 + r) * HIDDEN + 4 * k4]);
            acc[r][0] += a.x * w0.x + a.y * w1.x + a.z * w2.x + a.w * w3.x;
            acc[r][1] += a.x * w0.y + a.y * w1.y + a.z * w2.y + a.w * w3.y;
            acc[r][2] += a.x * w0.z + a.y * w1.z + a.z * w2.z + a.w * w3.z;
            acc[r][3] += a.x * w0.w + a.y * w1.w + a.z * w2.w + a.w * w3.w;
        }
    }

    float4 bias4 = make_float4(0.f, 0.f, 0.f, 0.f);
    if (BIAS) bias4 = *reinterpret_cast<const float4*>(bias + 4 * tx);

    __syncthreads();
#pragma unroll
    for (int r = 0; r < 8; r++) {
        float4 res = make_float4(acc[r][0], acc[r][1], acc[r][2], acc[r][3]);
        if (BIAS) {
            res.x += bias4.x; res.y += bias4.y; res.z += bias4.z; res.w += bias4.w;
        }
        As4[(ty * 8 + r) * 32 + tx] = res;
    }
    __syncthreads();

    float4* Cg = reinterpret_cast<float4*>(C);
#pragma unroll
    for (int i = 0; i < 8; i++) {
        const int idx = tid + i * 256;
        const int node = idx >> 5;
        const int c = (idx >> 2) & 7;
        const int f4 = idx & 3;
        if (r0 + node < nrows)
            Cg[((long)c * N_NODES + r0 + node) * 4 + f4] = As4[idx];
    }
}

// ---------------- fused SAGE GEMM: C = A1@Wl + A2@Wr + b (two-phase K) ----------

__global__ void gemm_sage(const float* __restrict__ A1, const float* __restrict__ Wl,
                          const float* __restrict__ A2, const float* __restrict__ Wr,
                          const float* __restrict__ bias, float* __restrict__ C,
                          int nrows) {
    __shared__ float As[64 * 128];
    const int r0 = blockIdx.x * 64;
    const int tid = threadIdx.x;
    float4* As4 = reinterpret_cast<float4*>(As);
    const int tx = tid & 31;
    const int ty = tid >> 5;

    float acc[8][4];
#pragma unroll
    for (int r = 0; r < 8; r++)
#pragma unroll
        for (int c = 0; c < 4; c++) acc[r][c] = 0.f;

    for (int p = 0; p < 2; p++) {
        const float* A = (p == 0) ? A1 : A2;
        const float* W = (p == 0) ? Wl : Wr;
        const float4* Ag = reinterpret_cast<const float4*>(A);
#pragma unroll
        for (int i = 0; i < 8; i++) {
            const int idx = tid + i * 256;
            const int node = idx >> 5;
            const int c = (idx >> 2) & 7;
            const int f4 = idx & 3;
            float4 v = make_float4(0.f, 0.f, 0.f, 0.f);
            if (r0 + node < nrows) v = Ag[((long)c * N_NODES + r0 + node) * 4 + f4];
            As4[idx] = v;
        }
        __syncthreads();

        const float4* Wg = reinterpret_cast<const float4*>(W);
        for (int k4 = 0; k4 < 32; k4++) {
            const float4 w0 = Wg[(4 * k4 + 0) * 32 + tx];
            const float4 w1 = Wg[(4 * k4 + 1) * 32 + tx];
            const float4 w2 = Wg[(4 * k4 + 2) * 32 + tx];
            const float4 w3 = Wg[(4 * k4 + 3) * 32 + tx];
#pragma unroll
            for (int r = 0; r < 8; r++) {
                const float4 a = *reinterpret_cast<const float4*>(&As[(ty * 8 + r) * HIDDEN + 4 * k4]);
                acc[r][0] += a.x * w0.x + a.y * w1.x + a.z * w2.x + a.w * w3.x;
                acc[r][1] += a.x * w0.y + a.y * w1.y + a.z * w2.y + a.w * w3.y;
                acc[r][2] += a.x * w0.z + a.y * w1.z + a.z * w2.z + a.w * w3.z;
                acc[r][3] += a.x * w0.w + a.y * w1.w + a.z * w2.w + a.w * w3.w;
            }
        }
        __syncthreads();
    }

    const float4 bias4 = *reinterpret_cast<const float4*>(bias + 4 * tx);
#pragma unroll
    for (int r = 0; r < 8; r++) {
        float4 res = make_float4(acc[r][0] + bias4.x, acc[r][1] + bias4.y,
                                 acc[r][2] + bias4.z, acc[r][3] + bias4.w);
        As4[(ty * 8 + r) * 32 + tx] = res;
    }
    __syncthreads();

    float4* Cg = reinterpret_cast<float4*>(C);
#pragma unroll
    for (int i = 0; i < 8; i++) {
        const int idx = tid + i * 256;
        const int node = idx >> 5;
        const int c = (idx >> 2) & 7;
        const int f4 = idx & 3;
        if (r0 + node < nrows)
            Cg[((long)c * N_NODES + r0 + node) * 4 + f4] = As4[idx];
    }
}

// ---------------- GCN gather (chunked): out = relu(sum h[s]*n + h[d]/deg + b) ----
// block: 256 thr = 4 waves; wave = 8 nodes x 8 lanes x float2; chunk = blockIdx%8.

__global__ void gather_gcn(const float* __restrict__ h, const int* __restrict__ rowptr,
                           const int* __restrict__ csr_src, const float* __restrict__ dinv,
                           const float* __restrict__ bias, float* __restrict__ out) {
    const int tid = threadIdx.x;
    const int chunk = blockIdx.x & 7;
    const int ngrp = blockIdx.x >> 3;
    const int lane = tid & 63;
    const int nio = lane >> 3;
    const int sub = lane & 7;
    const int d = ngrp * 32 + (tid >> 6) * 8 + nio;
    if (d >= N_NODES) return;
    const float di = dinv[d];
    const int beg = rowptr[d];
    const int end = rowptr[d + 1];
    const long cbase = (long)chunk * N_NODES;
    float ax = 0.f, ay = 0.f;
    for (int j = beg; j < end; j++) {
        const int s = csr_src[j];
        const float nrm = dinv[s] * di;
        const float2 v = *reinterpret_cast<const float2*>(h + (cbase + s) * 16 + sub * 2);
        ax += v.x * nrm;
        ay += v.y * nrm;
    }
    const float2 hv = *reinterpret_cast<const float2*>(h + (cbase + d) * 16 + sub * 2);
    const float2 b = *reinterpret_cast<const float2*>(bias + chunk * 16 + sub * 2);
    const float invdeg = di * di;
    float2 res;
    res.x = fmaxf(ax + hv.x * invdeg + b.x, 0.f);
    res.y = fmaxf(ay + hv.y * invdeg + b.y, 0.f);
    *reinterpret_cast<float2*>(out + (cbase + d) * 16 + sub * 2) = res;
}

// ---------------- SAGE mean gather (chunked) ----------------

__global__ void gather_sage(const float* __restrict__ h, const int* __restrict__ rowptr,
                            const int* __restrict__ csr_src, float* __restrict__ mean) {
    const int tid = threadIdx.x;
    const int chunk = blockIdx.x & 7;
    const int ngrp = blockIdx.x >> 3;
    const int lane = tid & 63;
    const int nio = lane >> 3;
    const int sub = lane & 7;
    const int d = ngrp * 32 + (tid >> 6) * 8 + nio;
    if (d >= N_NODES) return;
    const int beg = rowptr[d];
    const int end = rowptr[d + 1];
    const long cbase = (long)chunk * N_NODES;
    float ax = 0.f, ay = 0.f;
    for (int j = beg; j < end; j++) {
        const int s = csr_src[j];
        const float2 v = *reinterpret_cast<const float2*>(h + (cbase + s) * 16 + sub * 2);
        ax += v.x;
        ay += v.y;
    }
    const float inv = 1.0f / fmaxf((float)(end - beg), 1.0f);
    float2 res;
    res.x = ax * inv;
    res.y = ay * inv;
    *reinterpret_cast<float2*>(mean + (cbase + d) * 16 + sub * 2) = res;
}

// ---------------- pooling (two-stage; batch sorted; node input chunked) ---------

__device__ int lower_bound_batch(const int* __restrict__ batch, int key) {
    int lo = 0, hi = N_NODES;
    while (lo < hi) {
        int mid = (lo + hi) >> 1;
        if (batch[mid] < key) lo = mid + 1;
        else hi = mid;
    }
    return lo;
}

__global__ void pool_partial(const float* __restrict__ node, const int* __restrict__ batch,
                             float* __restrict__ part) {
    const int b = blockIdx.x;          // g * SLICES + k
    const int g = b / SLICES;
    const int k = b % SLICES;
    const int t = threadIdx.x;         // feature t
    const long cbase = (long)(t >> 4) * N_NODES;
    const int foff = t & 15;
    const int lo = lower_bound_batch(batch, g);
    const int hi = lower_bound_batch(batch, g + 1);
    const int len = hi - lo;
    const int per = (len + SLICES - 1) / SLICES;
    const int s = lo + k * per;
    const int e = min(s + per, hi);
    float acc = 0.f;
    for (int i = s; i < e; i++) acc += node[(cbase + i) * 16 + foff];
    part[(long)b * HIDDEN + t] = acc;
}

__global__ void pool_reduce(const float* __restrict__ part, const int* __restrict__ batch,
                            float* __restrict__ out) {
    const int g = blockIdx.x;
    const int t = threadIdx.x;
    float acc = 0.f;
#pragma unroll
    for (int k = 0; k < SLICES; k++) acc += part[(long)(g * SLICES + k) * HIDDEN + t];
    const int lo = lower_bound_batch(batch, g);
    const int hi = lower_bound_batch(batch, g + 1);
    out[g * HIDDEN + t] = acc / fmaxf((float)(hi - lo), 1.0f);
}

// ---------------- launch ----------------

extern "C" void kernel_launch(void* const* d_in, const int* in_sizes, int n_in,
                              void* d_out, int out_size, void* d_ws, size_t ws_size,
                              hipStream_t stream) {
    const float* x    = (const float*)d_in[0];
    const int*   ei   = (const int*)d_in[1];   // [2][E]
    const int*   batch= (const int*)d_in[2];
    const float* W1   = (const float*)d_in[3];
    const float* b1   = (const float*)d_in[4];
    const float* W2   = (const float*)d_in[5];
    const float* b2   = (const float*)d_in[6];
    const float* W_l  = (const float*)d_in[7];
    const float* W_r  = (const float*)d_in[8];
    const float* b_s  = (const float*)d_in[9];
    float* out = (float*)d_out;

    const int* src = ei;
    const int* dst = ei + N_EDGES;

    // workspace layout
    char* ws = (char*)d_ws;
    const size_t NB = (size_t)N_NODES * HIDDEN * sizeof(float);  // 25.6 MB
    float* B1 = (float*)(ws);                    // h buffer (chunked)
    float* B2 = (float*)(ws + NB);               // mean buffer (chunked)
    float* B3 = (float*)(ws + 2 * NB);           // layer output (chunked)
    size_t off = 3 * NB;
    int*   deg      = (int*)(ws + off);   off += (size_t)N_NODES * 4;
    float* dinv     = (float*)(ws + off); off += (size_t)N_NODES * 4;
    int*   rowptr   = (int*)(ws + off);   off += (size_t)(N_NODES + 1) * 4;
    int*   fillcnt  = (int*)(ws + off);   off += (size_t)N_NODES * 4;
    int*   csr_src  = (int*)(ws + off);   off += (size_t)N_EDGES * 4;
    float* part     = (float*)(ws + off); off += (size_t)N_GRAPHS * SLICES * HIDDEN * 4;
    int*   bsum     = (int*)(ws + off);   off += (size_t)SCAN_B * 4;
    int*   boff     = (int*)(ws + off);   off += (size_t)SCAN_B * 4;

    const int EB = (N_EDGES + 255) / 256;
    const int GB = (N_NODES + 63) / 64;
    const int WB = NG32 * 8;  // node-groups x chunks

    // ---- build CSR (once per call) ----
    hipMemsetAsync(deg, 0, (size_t)N_NODES * 4, stream);
    hipMemsetAsync(fillcnt, 0, (size_t)N_NODES * 4, stream);
    deg_kernel<<<EB, 256, 0, stream>>>(dst, deg);
    scan_partial<<<SCAN_B, 256, 0, stream>>>(deg, bsum);
    scan_bsum<<<1, 256, 0, stream>>>(bsum, boff, rowptr);
    scan_final<<<SCAN_B, 256, 0, stream>>>(deg, boff, rowptr, dinv);
    fill_kernel<<<EB, 256, 0, stream>>>(src, dst, rowptr, fillcnt, csr_src);

    // ---- GCN layer 1 ----
    gemm_kernel<false, false><<<GB, 256, 0, stream>>>(x, W1, B1, nullptr, N_NODES);
    gather_gcn<<<WB, 256, 0, stream>>>(B1, rowptr, csr_src, dinv, b1, B3);

    // ---- GCN layer 2 ----
    gemm_kernel<true, false><<<GB, 256, 0, stream>>>(B3, W2, B1, nullptr, N_NODES);
    gather_gcn<<<WB, 256, 0, stream>>>(B1, rowptr, csr_src, dinv, b2, B3);

    // ---- SAGE ----
    gather_sage<<<WB, 256, 0, stream>>>(B3, rowptr, csr_src, B2);
    gemm_sage<<<GB, 256, 0, stream>>>(B2, W_l, B3, W_r, b_s, B1, N_NODES);

    // ---- global mean pool (two-stage, no atomics) ----
    pool_partial<<<N_GRAPHS * SLICES, 128, 0, stream>>>(B1, batch, part);
    pool_reduce<<<N_GRAPHS, 128, 0, stream>>>(part, batch, out);
}

// Round 11
// 426.259 us; speedup vs baseline: 1.1640x; 1.1640x over previous
//
#include <hip/hip_runtime.h>

#define N_NODES 50000
#define N_EDGES 600000
#define HIDDEN 128
#define N_GRAPHS 64
#define SLICES 16
#define SCAN_B ((N_NODES + 255) / 256)   // 196
#define NG32 ((N_NODES + 31) / 32)       // 1563 node-groups of 32

// Feature-chunked layout for node matrices: elem(n,f) at
// ((f>>4) * N_NODES + n) * 16 + (f & 15).  Chunk = 3.2 MB -> fits XCD L2.

// ---------------- degree ----------------

__global__ void deg_kernel(const int* __restrict__ dst, int* __restrict__ deg) {
    int t = blockIdx.x * 256 + threadIdx.x;
    if (t < N_EDGES) atomicAdd(&deg[dst[t]], 1);
}

// ---------------- 3-pass parallel scan: deg -> rowptr (+ fused dinv) ----------------

__global__ void scan_partial(const int* __restrict__ deg, int* __restrict__ bsum) {
    const int b = blockIdx.x, t = threadIdx.x;
    const int i = b * 256 + t;
    int v = (i < N_NODES) ? deg[i] : 0;
    __shared__ int wsum[4];
#pragma unroll
    for (int o = 32; o > 0; o >>= 1) v += __shfl_down(v, o, 64);
    if ((t & 63) == 0) wsum[t >> 6] = v;
    __syncthreads();
    if (t == 0) bsum[b] = wsum[0] + wsum[1] + wsum[2] + wsum[3];
}

__global__ void scan_bsum(const int* __restrict__ bsum, int* __restrict__ boff,
                          int* __restrict__ rowptr) {
    __shared__ int s[256];
    const int t = threadIdx.x;
    const int v = (t < SCAN_B) ? bsum[t] : 0;
    s[t] = v;
    __syncthreads();
    for (int o = 1; o < 256; o <<= 1) {
        int u = (t >= o) ? s[t - o] : 0;
        __syncthreads();
        s[t] += u;
        __syncthreads();
    }
    if (t < SCAN_B) boff[t] = s[t] - v;      // exclusive
    if (t == 255) rowptr[N_NODES] = s[255];  // total == N_EDGES
}

__global__ void scan_final(const int* __restrict__ deg, const int* __restrict__ boff,
                           int* __restrict__ rowptr, float* __restrict__ dinv) {
    const int b = blockIdx.x, t = threadIdx.x;
    const int i = b * 256 + t;
    __shared__ int s[256];
    const int v = (i < N_NODES) ? deg[i] : 0;
    s[t] = v;
    __syncthreads();
    for (int o = 1; o < 256; o <<= 1) {
        int u = (t >= o) ? s[t - o] : 0;
        __syncthreads();
        s[t] += u;
        __syncthreads();
    }
    if (i < N_NODES) {
        rowptr[i] = boff[b] + s[t] - v;
        dinv[i] = rsqrtf((float)v + 1.0f);
    }
}

// ---------------- CSR fill: interleaved {src, norm} ----------------

__global__ void fill_kernel(const int* __restrict__ src, const int* __restrict__ dst,
                            const int* __restrict__ rowptr, int* __restrict__ fillcnt,
                            const float* __restrict__ dinv, int2* __restrict__ csr) {
    int e = blockIdx.x * 256 + threadIdx.x;
    if (e >= N_EDGES) return;
    const int d = dst[e];
    const int s = src[e];
    const int pos = rowptr[d] + atomicAdd(&fillcnt[d], 1);
    csr[pos] = make_int2(s, __float_as_int(dinv[s] * dinv[d]));
}

// ---------------- GEMM: C_chunked = A @ W ; 32-row tile, 256 thr ----------------
// CHA: A feature-chunked; else row-major. C always chunked.

template <bool CHA, bool BIAS>
__global__ void gemm_kernel(const float* __restrict__ A, const float* __restrict__ W,
                            float* __restrict__ C, const float* __restrict__ bias,
                            int nrows) {
    __shared__ float As[32 * 128];
    const int r0 = blockIdx.x * 32;
    const int tid = threadIdx.x;
    float4* As4 = reinterpret_cast<float4*>(As);

    if (CHA) {
        const float4* Ag = reinterpret_cast<const float4*>(A);
#pragma unroll
        for (int i = 0; i < 4; i++) {
            const int idx = tid + i * 256;       // 0..1023
            const int node = idx >> 5;           // 0..31
            const int c = (idx >> 2) & 7;
            const int f4 = idx & 3;
            float4 v = make_float4(0.f, 0.f, 0.f, 0.f);
            if (r0 + node < nrows) v = Ag[((long)c * N_NODES + r0 + node) * 4 + f4];
            As4[idx] = v;                        // row-major [node][feature]
        }
    } else {
        const float4* Ag = reinterpret_cast<const float4*>(A + (long)r0 * HIDDEN);
        const int maxv = (nrows - r0) * 32;
#pragma unroll
        for (int i = 0; i < 4; i++) {
            int idx = tid + i * 256;
            float4 v = make_float4(0.f, 0.f, 0.f, 0.f);
            if (idx < maxv) v = Ag[idx];
            As4[idx] = v;
        }
    }
    __syncthreads();

    const int tx = tid & 31;
    const int ty = tid >> 5;   // 0..7 -> rows ty*4..+3

    float acc[4][4];
#pragma unroll
    for (int r = 0; r < 4; r++)
#pragma unroll
        for (int c = 0; c < 4; c++) acc[r][c] = 0.f;

    const float4* Wg = reinterpret_cast<const float4*>(W);
    for (int k4 = 0; k4 < 32; k4++) {
        const float4 w0 = Wg[(4 * k4 + 0) * 32 + tx];
        const float4 w1 = Wg[(4 * k4 + 1) * 32 + tx];
        const float4 w2 = Wg[(4 * k4 + 2) * 32 + tx];
        const float4 w3 = Wg[(4 * k4 + 3) * 32 + tx];
#pragma unroll
        for (int r = 0; r < 4; r++) {
            const float4 a = *reinterpret_cast<const float4*>(&As[(ty * 4 + r) * HIDDEN + 4 * k4]);
            acc[r][0] += a.x * w0.x + a.y * w1.x + a.z * w2.x + a.w * w3.x;
            acc[r][1] += a.x * w0.y + a.y * w1.y + a.z * w2.y + a.w * w3.y;
            acc[r][2] += a.x * w0.z + a.y * w1.z + a.z * w2.z + a.w * w3.z;
            acc[r][3] += a.x * w0.w + a.y * w1.w + a.z * w2.w + a.w * w3.w;
        }
    }

    float4 bias4 = make_float4(0.f, 0.f, 0.f, 0.f);
    if (BIAS) bias4 = *reinterpret_cast<const float4*>(bias + 4 * tx);

    __syncthreads();
#pragma unroll
    for (int r = 0; r < 4; r++) {
        float4 res = make_float4(acc[r][0], acc[r][1], acc[r][2], acc[r][3]);
        if (BIAS) {
            res.x += bias4.x; res.y += bias4.y; res.z += bias4.z; res.w += bias4.w;
        }
        As4[(ty * 4 + r) * 32 + tx] = res;
    }
    __syncthreads();

    float4* Cg = reinterpret_cast<float4*>(C);
#pragma unroll
    for (int i = 0; i < 4; i++) {
        const int idx = tid + i * 256;
        const int node = idx >> 5;
        const int c = (idx >> 2) & 7;
        const int f4 = idx & 3;
        if (r0 + node < nrows)
            Cg[((long)c * N_NODES + r0 + node) * 4 + f4] = As4[idx];
    }
}

// ---------------- fused SAGE GEMM: C = A1@Wl + A2@Wr + b (two-phase K) ----------

__global__ void gemm_sage(const float* __restrict__ A1, const float* __restrict__ Wl,
                          const float* __restrict__ A2, const float* __restrict__ Wr,
                          const float* __restrict__ bias, float* __restrict__ C,
                          int nrows) {
    __shared__ float As[32 * 128];
    const int r0 = blockIdx.x * 32;
    const int tid = threadIdx.x;
    float4* As4 = reinterpret_cast<float4*>(As);
    const int tx = tid & 31;
    const int ty = tid >> 5;

    float acc[4][4];
#pragma unroll
    for (int r = 0; r < 4; r++)
#pragma unroll
        for (int c = 0; c < 4; c++) acc[r][c] = 0.f;

    for (int p = 0; p < 2; p++) {
        const float* A = (p == 0) ? A1 : A2;
        const float* W = (p == 0) ? Wl : Wr;
        const float4* Ag = reinterpret_cast<const float4*>(A);
        if (p) __syncthreads();
#pragma unroll
        for (int i = 0; i < 4; i++) {
            const int idx = tid + i * 256;
            const int node = idx >> 5;
            const int c = (idx >> 2) & 7;
            const int f4 = idx & 3;
            float4 v = make_float4(0.f, 0.f, 0.f, 0.f);
            if (r0 + node < nrows) v = Ag[((long)c * N_NODES + r0 + node) * 4 + f4];
            As4[idx] = v;
        }
        __syncthreads();

        const float4* Wg = reinterpret_cast<const float4*>(W);
        for (int k4 = 0; k4 < 32; k4++) {
            const float4 w0 = Wg[(4 * k4 + 0) * 32 + tx];
            const float4 w1 = Wg[(4 * k4 + 1) * 32 + tx];
            const float4 w2 = Wg[(4 * k4 + 2) * 32 + tx];
            const float4 w3 = Wg[(4 * k4 + 3) * 32 + tx];
#pragma unroll
            for (int r = 0; r < 4; r++) {
                const float4 a = *reinterpret_cast<const float4*>(&As[(ty * 4 + r) * HIDDEN + 4 * k4]);
                acc[r][0] += a.x * w0.x + a.y * w1.x + a.z * w2.x + a.w * w3.x;
                acc[r][1] += a.x * w0.y + a.y * w1.y + a.z * w2.y + a.w * w3.y;
                acc[r][2] += a.x * w0.z + a.y * w1.z + a.z * w2.z + a.w * w3.z;
                acc[r][3] += a.x * w0.w + a.y * w1.w + a.z * w2.w + a.w * w3.w;
            }
        }
    }

    const float4 bias4 = *reinterpret_cast<const float4*>(bias + 4 * tx);
    __syncthreads();
#pragma unroll
    for (int r = 0; r < 4; r++) {
        float4 res = make_float4(acc[r][0] + bias4.x, acc[r][1] + bias4.y,
                                 acc[r][2] + bias4.z, acc[r][3] + bias4.w);
        As4[(ty * 4 + r) * 32 + tx] = res;
    }
    __syncthreads();

    float4* Cg = reinterpret_cast<float4*>(C);
#pragma unroll
    for (int i = 0; i < 4; i++) {
        const int idx = tid + i * 256;
        const int node = idx >> 5;
        const int c = (idx >> 2) & 7;
        const int f4 = idx & 3;
        if (r0 + node < nrows)
            Cg[((long)c * N_NODES + r0 + node) * 4 + f4] = As4[idx];
    }
}

// ---------------- GCN gather (chunked): out = relu(sum h[s]*n + h[d]/deg + b) ----
// block: 256 thr = 4 waves; wave = 8 nodes x 8 lanes x float2; chunk = blockIdx%8.

__global__ void gather_gcn(const float* __restrict__ h, const int* __restrict__ rowptr,
                           const int2* __restrict__ csr, const float* __restrict__ dinv,
                           const float* __restrict__ bias, float* __restrict__ out) {
    const int tid = threadIdx.x;
    const int chunk = blockIdx.x & 7;
    const int ngrp = blockIdx.x >> 3;
    const int lane = tid & 63;
    const int nio = lane >> 3;
    const int sub = lane & 7;
    const int d = ngrp * 32 + (tid >> 6) * 8 + nio;
    if (d >= N_NODES) return;
    const float di = dinv[d];
    const int beg = rowptr[d];
    const int end = rowptr[d + 1];
    const long cbase = (long)chunk * N_NODES;
    float ax = 0.f, ay = 0.f;
    int j = beg;
    for (; j + 2 <= end; j += 2) {
        const int2 e0 = csr[j];
        const int2 e1 = csr[j + 1];
        const float n0 = __int_as_float(e0.y);
        const float n1 = __int_as_float(e1.y);
        const float2 v0 = *reinterpret_cast<const float2*>(h + (cbase + e0.x) * 16 + sub * 2);
        const float2 v1 = *reinterpret_cast<const float2*>(h + (cbase + e1.x) * 16 + sub * 2);
        ax += v0.x * n0 + v1.x * n1;
        ay += v0.y * n0 + v1.y * n1;
    }
    if (j < end) {
        const int2 e0 = csr[j];
        const float n0 = __int_as_float(e0.y);
        const float2 v0 = *reinterpret_cast<const float2*>(h + (cbase + e0.x) * 16 + sub * 2);
        ax += v0.x * n0;
        ay += v0.y * n0;
    }
    const float2 hv = *reinterpret_cast<const float2*>(h + (cbase + d) * 16 + sub * 2);
    const float2 b = *reinterpret_cast<const float2*>(bias + chunk * 16 + sub * 2);
    const float invdeg = di * di;
    float2 res;
    res.x = fmaxf(ax + hv.x * invdeg + b.x, 0.f);
    res.y = fmaxf(ay + hv.y * invdeg + b.y, 0.f);
    *reinterpret_cast<float2*>(out + (cbase + d) * 16 + sub * 2) = res;
}

// ---------------- SAGE mean gather (chunked) ----------------

__global__ void gather_sage(const float* __restrict__ h, const int* __restrict__ rowptr,
                            const int2* __restrict__ csr, float* __restrict__ mean) {
    const int tid = threadIdx.x;
    const int chunk = blockIdx.x & 7;
    const int ngrp = blockIdx.x >> 3;
    const int lane = tid & 63;
    const int nio = lane >> 3;
    const int sub = lane & 7;
    const int d = ngrp * 32 + (tid >> 6) * 8 + nio;
    if (d >= N_NODES) return;
    const int beg = rowptr[d];
    const int end = rowptr[d + 1];
    const long cbase = (long)chunk * N_NODES;
    float ax = 0.f, ay = 0.f;
    int j = beg;
    for (; j + 2 <= end; j += 2) {
        const int2 e0 = csr[j];
        const int2 e1 = csr[j + 1];
        const float2 v0 = *reinterpret_cast<const float2*>(h + (cbase + e0.x) * 16 + sub * 2);
        const float2 v1 = *reinterpret_cast<const float2*>(h + (cbase + e1.x) * 16 + sub * 2);
        ax += v0.x + v1.x;
        ay += v0.y + v1.y;
    }
    if (j < end) {
        const int2 e0 = csr[j];
        const float2 v0 = *reinterpret_cast<const float2*>(h + (cbase + e0.x) * 16 + sub * 2);
        ax += v0.x;
        ay += v0.y;
    }
    const float inv = 1.0f / fmaxf((float)(end - beg), 1.0f);
    float2 res;
    res.x = ax * inv;
    res.y = ay * inv;
    *reinterpret_cast<float2*>(mean + (cbase + d) * 16 + sub * 2) = res;
}

// ---------------- pooling (two-stage; batch sorted; node input chunked) ---------

__device__ int lower_bound_batch(const int* __restrict__ batch, int key) {
    int lo = 0, hi = N_NODES;
    while (lo < hi) {
        int mid = (lo + hi) >> 1;
        if (batch[mid] < key) lo = mid + 1;
        else hi = mid;
    }
    return lo;
}

__global__ void pool_partial(const float* __restrict__ node, const int* __restrict__ batch,
                             float* __restrict__ part) {
    const int b = blockIdx.x;          // g * SLICES + k
    const int g = b / SLICES;
    const int k = b % SLICES;
    const int t = threadIdx.x;         // feature t
    const long cbase = (long)(t >> 4) * N_NODES;
    const int foff = t & 15;
    const int lo = lower_bound_batch(batch, g);
    const int hi = lower_bound_batch(batch, g + 1);
    const int len = hi - lo;
    const int per = (len + SLICES - 1) / SLICES;
    const int s = lo + k * per;
    const int e = min(s + per, hi);
    float acc = 0.f;
    for (int i = s; i < e; i++) acc += node[(cbase + i) * 16 + foff];
    part[(long)b * HIDDEN + t] = acc;
}

__global__ void pool_reduce(const float* __restrict__ part, const int* __restrict__ batch,
                            float* __restrict__ out) {
    const int g = blockIdx.x;
    const int t = threadIdx.x;
    float acc = 0.f;
#pragma unroll
    for (int k = 0; k < SLICES; k++) acc += part[(long)(g * SLICES + k) * HIDDEN + t];
    const int lo = lower_bound_batch(batch, g);
    const int hi = lower_bound_batch(batch, g + 1);
    out[g * HIDDEN + t] = acc / fmaxf((float)(hi - lo), 1.0f);
}

// ---------------- launch ----------------

extern "C" void kernel_launch(void* const* d_in, const int* in_sizes, int n_in,
                              void* d_out, int out_size, void* d_ws, size_t ws_size,
                              hipStream_t stream) {
    const float* x    = (const float*)d_in[0];
    const int*   ei   = (const int*)d_in[1];   // [2][E]
    const int*   batch= (const int*)d_in[2];
    const float* W1   = (const float*)d_in[3];
    const float* b1   = (const float*)d_in[4];
    const float* W2   = (const float*)d_in[5];
    const float* b2   = (const float*)d_in[6];
    const float* W_l  = (const float*)d_in[7];
    const float* W_r  = (const float*)d_in[8];
    const float* b_s  = (const float*)d_in[9];
    float* out = (float*)d_out;

    const int* src = ei;
    const int* dst = ei + N_EDGES;

    // workspace layout
    char* ws = (char*)d_ws;
    const size_t NB = (size_t)N_NODES * HIDDEN * sizeof(float);  // 25.6 MB
    float* B1 = (float*)(ws);                    // h buffer (chunked)
    float* B2 = (float*)(ws + NB);               // mean buffer (chunked)
    float* B3 = (float*)(ws + 2 * NB);           // layer output (chunked)
    size_t off = 3 * NB;
    int*   deg      = (int*)(ws + off);   off += (size_t)N_NODES * 4;
    float* dinv     = (float*)(ws + off); off += (size_t)N_NODES * 4;
    int*   rowptr   = (int*)(ws + off);   off += (size_t)(N_NODES + 1) * 4;
    int*   fillcnt  = (int*)(ws + off);   off += (size_t)N_NODES * 4;
    int2*  csr      = (int2*)(ws + off);  off += (size_t)N_EDGES * 8;
    float* part     = (float*)(ws + off); off += (size_t)N_GRAPHS * SLICES * HIDDEN * 4;
    int*   bsum     = (int*)(ws + off);   off += (size_t)SCAN_B * 4;
    int*   boff     = (int*)(ws + off);   off += (size_t)SCAN_B * 4;

    const int EB = (N_EDGES + 255) / 256;
    const int GB = (N_NODES + 31) / 32;   // 32-row GEMM tiles
    const int WB = NG32 * 8;              // node-groups x chunks

    // ---- build CSR (once per call) ----
    hipMemsetAsync(deg, 0, (size_t)N_NODES * 4, stream);
    hipMemsetAsync(fillcnt, 0, (size_t)N_NODES * 4, stream);
    deg_kernel<<<EB, 256, 0, stream>>>(dst, deg);
    scan_partial<<<SCAN_B, 256, 0, stream>>>(deg, bsum);
    scan_bsum<<<1, 256, 0, stream>>>(bsum, boff, rowptr);
    scan_final<<<SCAN_B, 256, 0, stream>>>(deg, boff, rowptr, dinv);
    fill_kernel<<<EB, 256, 0, stream>>>(src, dst, rowptr, fillcnt, dinv, csr);

    // ---- GCN layer 1 ----
    gemm_kernel<false, false><<<GB, 256, 0, stream>>>(x, W1, B1, nullptr, N_NODES);
    gather_gcn<<<WB, 256, 0, stream>>>(B1, rowptr, csr, dinv, b1, B3);

    // ---- GCN layer 2 ----
    gemm_kernel<true, false><<<GB, 256, 0, stream>>>(B3, W2, B1, nullptr, N_NODES);
    gather_gcn<<<WB, 256, 0, stream>>>(B1, rowptr, csr, dinv, b2, B3);

    // ---- SAGE ----
    gather_sage<<<WB, 256, 0, stream>>>(B3, rowptr, csr, B2);
    gemm_sage<<<GB, 256, 0, stream>>>(B2, W_l, B3, W_r, b_s, B1, N_NODES);

    // ---- global mean pool (two-stage, no atomics) ----
    pool_partial<<<N_GRAPHS * SLICES, 128, 0, stream>>>(B1, batch, part);
    pool_reduce<<<N_GRAPHS, 128, 0, stream>>>(part, batch, out);
}

// Round 12
// 418.335 us; speedup vs baseline: 1.1861x; 1.0189x over previous
//
#include <hip/hip_runtime.h>

#define N_NODES 50000
#define N_EDGES 600000
#define HIDDEN 128
#define N_GRAPHS 64
#define SLICES 16
#define SCAN_B ((N_NODES + 255) / 256)   // 196
#define NG32 ((N_NODES + 31) / 32)       // 1563 node-groups of 32

// Feature-chunked layout for node matrices: elem(n,f) at
// ((f>>4) * N_NODES + n) * 16 + (f & 15).  Chunk = 3.2 MB -> fits XCD L2.

// ---------------- degree ----------------

__global__ void deg_kernel(const int* __restrict__ dst, int* __restrict__ deg) {
    int t = blockIdx.x * 256 + threadIdx.x;
    if (t < N_EDGES) atomicAdd(&deg[dst[t]], 1);
}

// ---------------- 3-pass parallel scan: deg -> rowptr (+ fused dinv) ----------------

__global__ void scan_partial(const int* __restrict__ deg, int* __restrict__ bsum) {
    const int b = blockIdx.x, t = threadIdx.x;
    const int i = b * 256 + t;
    int v = (i < N_NODES) ? deg[i] : 0;
    __shared__ int wsum[4];
#pragma unroll
    for (int o = 32; o > 0; o >>= 1) v += __shfl_down(v, o, 64);
    if ((t & 63) == 0) wsum[t >> 6] = v;
    __syncthreads();
    if (t == 0) bsum[b] = wsum[0] + wsum[1] + wsum[2] + wsum[3];
}

__global__ void scan_bsum(const int* __restrict__ bsum, int* __restrict__ boff,
                          int* __restrict__ rowptr) {
    __shared__ int s[256];
    const int t = threadIdx.x;
    const int v = (t < SCAN_B) ? bsum[t] : 0;
    s[t] = v;
    __syncthreads();
    for (int o = 1; o < 256; o <<= 1) {
        int u = (t >= o) ? s[t - o] : 0;
        __syncthreads();
        s[t] += u;
        __syncthreads();
    }
    if (t < SCAN_B) boff[t] = s[t] - v;      // exclusive
    if (t == 255) rowptr[N_NODES] = s[255];  // total == N_EDGES
}

__global__ void scan_final(const int* __restrict__ deg, const int* __restrict__ boff,
                           int* __restrict__ rowptr, float* __restrict__ dinv) {
    const int b = blockIdx.x, t = threadIdx.x;
    const int i = b * 256 + t;
    __shared__ int s[256];
    const int v = (i < N_NODES) ? deg[i] : 0;
    s[t] = v;
    __syncthreads();
    for (int o = 1; o < 256; o <<= 1) {
        int u = (t >= o) ? s[t - o] : 0;
        __syncthreads();
        s[t] += u;
        __syncthreads();
    }
    if (i < N_NODES) {
        rowptr[i] = boff[b] + s[t] - v;
        dinv[i] = rsqrtf((float)v + 1.0f);
    }
}

// ---------------- CSR fill: interleaved {src, norm} ----------------

__global__ void fill_kernel(const int* __restrict__ src, const int* __restrict__ dst,
                            const int* __restrict__ rowptr, int* __restrict__ fillcnt,
                            const float* __restrict__ dinv, int2* __restrict__ csr) {
    int e = blockIdx.x * 256 + threadIdx.x;
    if (e >= N_EDGES) return;
    const int d = dst[e];
    const int s = src[e];
    const int pos = rowptr[d] + atomicAdd(&fillcnt[d], 1);
    csr[pos] = make_int2(s, __float_as_int(dinv[s] * dinv[d]));
}

// FMA micro-block: acc[r][*] += a(row r, quad k4) . w{0..3}
#define FMA_ROW(r, K4, W0, W1, W2, W3)                                              \
    {                                                                               \
        const float4 a = *reinterpret_cast<const float4*>(                          \
            &As[(ty * 4 + (r)) * HIDDEN + 4 * (K4)]);                               \
        acc[r][0] += a.x * W0.x + a.y * W1.x + a.z * W2.x + a.w * W3.x;             \
        acc[r][1] += a.x * W0.y + a.y * W1.y + a.z * W2.y + a.w * W3.y;             \
        acc[r][2] += a.x * W0.z + a.y * W1.z + a.z * W2.z + a.w * W3.z;             \
        acc[r][3] += a.x * W0.w + a.y * W1.w + a.z * W2.w + a.w * W3.w;             \
    }

// ---------------- GEMM: C_chunked = A @ W ; 32-row tile, 256 thr ----------------
// CHA: A feature-chunked; else row-major. C always chunked.
// k-loop 2x unrolled with ping-pong W prefetch (hide L2 latency under FMAs).

template <bool CHA, bool BIAS>
__global__ void gemm_kernel(const float* __restrict__ A, const float* __restrict__ W,
                            float* __restrict__ C, const float* __restrict__ bias,
                            int nrows) {
    __shared__ float As[32 * 128];
    const int r0 = blockIdx.x * 32;
    const int tid = threadIdx.x;
    float4* As4 = reinterpret_cast<float4*>(As);

    if (CHA) {
        const float4* Ag = reinterpret_cast<const float4*>(A);
#pragma unroll
        for (int i = 0; i < 4; i++) {
            const int idx = tid + i * 256;       // 0..1023
            const int node = idx >> 5;           // 0..31
            const int c = (idx >> 2) & 7;
            const int f4 = idx & 3;
            float4 v = make_float4(0.f, 0.f, 0.f, 0.f);
            if (r0 + node < nrows) v = Ag[((long)c * N_NODES + r0 + node) * 4 + f4];
            As4[idx] = v;                        // row-major [node][feature]
        }
    } else {
        const float4* Ag = reinterpret_cast<const float4*>(A + (long)r0 * HIDDEN);
        const int maxv = (nrows - r0) * 32;
#pragma unroll
        for (int i = 0; i < 4; i++) {
            int idx = tid + i * 256;
            float4 v = make_float4(0.f, 0.f, 0.f, 0.f);
            if (idx < maxv) v = Ag[idx];
            As4[idx] = v;
        }
    }
    __syncthreads();

    const int tx = tid & 31;
    const int ty = tid >> 5;   // 0..7 -> rows ty*4..+3

    float acc[4][4];
#pragma unroll
    for (int r = 0; r < 4; r++)
#pragma unroll
        for (int c = 0; c < 4; c++) acc[r][c] = 0.f;

    const float4* Wg = reinterpret_cast<const float4*>(W);
    float4 wa0 = Wg[0 * 32 + tx], wa1 = Wg[1 * 32 + tx];
    float4 wa2 = Wg[2 * 32 + tx], wa3 = Wg[3 * 32 + tx];
    float4 wb0, wb1, wb2, wb3;

    for (int k4 = 0; k4 < 32; k4 += 2) {
        const int kb = 4 * (k4 + 1);
        wb0 = Wg[(kb + 0) * 32 + tx];
        wb1 = Wg[(kb + 1) * 32 + tx];
        wb2 = Wg[(kb + 2) * 32 + tx];
        wb3 = Wg[(kb + 3) * 32 + tx];
        FMA_ROW(0, k4, wa0, wa1, wa2, wa3)
        FMA_ROW(1, k4, wa0, wa1, wa2, wa3)
        FMA_ROW(2, k4, wa0, wa1, wa2, wa3)
        FMA_ROW(3, k4, wa0, wa1, wa2, wa3)
        if (k4 + 2 < 32) {
            const int ka = 4 * (k4 + 2);
            wa0 = Wg[(ka + 0) * 32 + tx];
            wa1 = Wg[(ka + 1) * 32 + tx];
            wa2 = Wg[(ka + 2) * 32 + tx];
            wa3 = Wg[(ka + 3) * 32 + tx];
        }
        FMA_ROW(0, k4 + 1, wb0, wb1, wb2, wb3)
        FMA_ROW(1, k4 + 1, wb0, wb1, wb2, wb3)
        FMA_ROW(2, k4 + 1, wb0, wb1, wb2, wb3)
        FMA_ROW(3, k4 + 1, wb0, wb1, wb2, wb3)
    }

    float4 bias4 = make_float4(0.f, 0.f, 0.f, 0.f);
    if (BIAS) bias4 = *reinterpret_cast<const float4*>(bias + 4 * tx);

    __syncthreads();
#pragma unroll
    for (int r = 0; r < 4; r++) {
        float4 res = make_float4(acc[r][0], acc[r][1], acc[r][2], acc[r][3]);
        if (BIAS) {
            res.x += bias4.x; res.y += bias4.y; res.z += bias4.z; res.w += bias4.w;
        }
        As4[(ty * 4 + r) * 32 + tx] = res;
    }
    __syncthreads();

    float4* Cg = reinterpret_cast<float4*>(C);
#pragma unroll
    for (int i = 0; i < 4; i++) {
        const int idx = tid + i * 256;
        const int node = idx >> 5;
        const int c = (idx >> 2) & 7;
        const int f4 = idx & 3;
        if (r0 + node < nrows)
            Cg[((long)c * N_NODES + r0 + node) * 4 + f4] = As4[idx];
    }
}

// ---------------- fused SAGE GEMM: C = A1@Wl + A2@Wr + b (two-phase K) ----------

__global__ void gemm_sage(const float* __restrict__ A1, const float* __restrict__ Wl,
                          const float* __restrict__ A2, const float* __restrict__ Wr,
                          const float* __restrict__ bias, float* __restrict__ C,
                          int nrows) {
    __shared__ float As[32 * 128];
    const int r0 = blockIdx.x * 32;
    const int tid = threadIdx.x;
    float4* As4 = reinterpret_cast<float4*>(As);
    const int tx = tid & 31;
    const int ty = tid >> 5;

    float acc[4][4];
#pragma unroll
    for (int r = 0; r < 4; r++)
#pragma unroll
        for (int c = 0; c < 4; c++) acc[r][c] = 0.f;

    for (int p = 0; p < 2; p++) {
        const float* A = (p == 0) ? A1 : A2;
        const float* W = (p == 0) ? Wl : Wr;
        const float4* Ag = reinterpret_cast<const float4*>(A);
        if (p) __syncthreads();
#pragma unroll
        for (int i = 0; i < 4; i++) {
            const int idx = tid + i * 256;
            const int node = idx >> 5;
            const int c = (idx >> 2) & 7;
            const int f4 = idx & 3;
            float4 v = make_float4(0.f, 0.f, 0.f, 0.f);
            if (r0 + node < nrows) v = Ag[((long)c * N_NODES + r0 + node) * 4 + f4];
            As4[idx] = v;
        }
        __syncthreads();

        const float4* Wg = reinterpret_cast<const float4*>(W);
        float4 wa0 = Wg[0 * 32 + tx], wa1 = Wg[1 * 32 + tx];
        float4 wa2 = Wg[2 * 32 + tx], wa3 = Wg[3 * 32 + tx];
        float4 wb0, wb1, wb2, wb3;

        for (int k4 = 0; k4 < 32; k4 += 2) {
            const int kb = 4 * (k4 + 1);
            wb0 = Wg[(kb + 0) * 32 + tx];
            wb1 = Wg[(kb + 1) * 32 + tx];
            wb2 = Wg[(kb + 2) * 32 + tx];
            wb3 = Wg[(kb + 3) * 32 + tx];
            FMA_ROW(0, k4, wa0, wa1, wa2, wa3)
            FMA_ROW(1, k4, wa0, wa1, wa2, wa3)
            FMA_ROW(2, k4, wa0, wa1, wa2, wa3)
            FMA_ROW(3, k4, wa0, wa1, wa2, wa3)
            if (k4 + 2 < 32) {
                const int ka = 4 * (k4 + 2);
                wa0 = Wg[(ka + 0) * 32 + tx];
                wa1 = Wg[(ka + 1) * 32 + tx];
                wa2 = Wg[(ka + 2) * 32 + tx];
                wa3 = Wg[(ka + 3) * 32 + tx];
            }
            FMA_ROW(0, k4 + 1, wb0, wb1, wb2, wb3)
            FMA_ROW(1, k4 + 1, wb0, wb1, wb2, wb3)
            FMA_ROW(2, k4 + 1, wb0, wb1, wb2, wb3)
            FMA_ROW(3, k4 + 1, wb0, wb1, wb2, wb3)
        }
    }

    const float4 bias4 = *reinterpret_cast<const float4*>(bias + 4 * tx);
    __syncthreads();
#pragma unroll
    for (int r = 0; r < 4; r++) {
        float4 res = make_float4(acc[r][0] + bias4.x, acc[r][1] + bias4.y,
                                 acc[r][2] + bias4.z, acc[r][3] + bias4.w);
        As4[(ty * 4 + r) * 32 + tx] = res;
    }
    __syncthreads();

    float4* Cg = reinterpret_cast<float4*>(C);
#pragma unroll
    for (int i = 0; i < 4; i++) {
        const int idx = tid + i * 256;
        const int node = idx >> 5;
        const int c = (idx >> 2) & 7;
        const int f4 = idx & 3;
        if (r0 + node < nrows)
            Cg[((long)c * N_NODES + r0 + node) * 4 + f4] = As4[idx];
    }
}

// ---------------- GCN gather (chunked): out = relu(sum h[s]*n + h[d]/deg + b) ----
// block: 256 thr = 4 waves; wave = 8 nodes x 8 lanes x float2; chunk = blockIdx%8.

__global__ void gather_gcn(const float* __restrict__ h, const int* __restrict__ rowptr,
                           const int2* __restrict__ csr, const float* __restrict__ dinv,
                           const float* __restrict__ bias, float* __restrict__ out) {
    const int tid = threadIdx.x;
    const int chunk = blockIdx.x & 7;
    const int ngrp = blockIdx.x >> 3;
    const int lane = tid & 63;
    const int nio = lane >> 3;
    const int sub = lane & 7;
    const int d = ngrp * 32 + (tid >> 6) * 8 + nio;
    if (d >= N_NODES) return;
    const float di = dinv[d];
    const int beg = rowptr[d];
    const int end = rowptr[d + 1];
    const long cbase = (long)chunk * N_NODES;
    float ax = 0.f, ay = 0.f;
    int j = beg;
    for (; j + 2 <= end; j += 2) {
        const int2 e0 = csr[j];
        const int2 e1 = csr[j + 1];
        const float n0 = __int_as_float(e0.y);
        const float n1 = __int_as_float(e1.y);
        const float2 v0 = *reinterpret_cast<const float2*>(h + (cbase + e0.x) * 16 + sub * 2);
        const float2 v1 = *reinterpret_cast<const float2*>(h + (cbase + e1.x) * 16 + sub * 2);
        ax += v0.x * n0 + v1.x * n1;
        ay += v0.y * n0 + v1.y * n1;
    }
    if (j < end) {
        const int2 e0 = csr[j];
        const float n0 = __int_as_float(e0.y);
        const float2 v0 = *reinterpret_cast<const float2*>(h + (cbase + e0.x) * 16 + sub * 2);
        ax += v0.x * n0;
        ay += v0.y * n0;
    }
    const float2 hv = *reinterpret_cast<const float2*>(h + (cbase + d) * 16 + sub * 2);
    const float2 b = *reinterpret_cast<const float2*>(bias + chunk * 16 + sub * 2);
    const float invdeg = di * di;
    float2 res;
    res.x = fmaxf(ax + hv.x * invdeg + b.x, 0.f);
    res.y = fmaxf(ay + hv.y * invdeg + b.y, 0.f);
    *reinterpret_cast<float2*>(out + (cbase + d) * 16 + sub * 2) = res;
}

// ---------------- SAGE mean gather (chunked) ----------------

__global__ void gather_sage(const float* __restrict__ h, const int* __restrict__ rowptr,
                            const int2* __restrict__ csr, float* __restrict__ mean) {
    const int tid = threadIdx.x;
    const int chunk = blockIdx.x & 7;
    const int ngrp = blockIdx.x >> 3;
    const int lane = tid & 63;
    const int nio = lane >> 3;
    const int sub = lane & 7;
    const int d = ngrp * 32 + (tid >> 6) * 8 + nio;
    if (d >= N_NODES) return;
    const int beg = rowptr[d];
    const int end = rowptr[d + 1];
    const long cbase = (long)chunk * N_NODES;
    float ax = 0.f, ay = 0.f;
    int j = beg;
    for (; j + 2 <= end; j += 2) {
        const int2 e0 = csr[j];
        const int2 e1 = csr[j + 1];
        const float2 v0 = *reinterpret_cast<const float2*>(h + (cbase + e0.x) * 16 + sub * 2);
        const float2 v1 = *reinterpret_cast<const float2*>(h + (cbase + e1.x) * 16 + sub * 2);
        ax += v0.x + v1.x;
        ay += v0.y + v1.y;
    }
    if (j < end) {
        const int2 e0 = csr[j];
        const float2 v0 = *reinterpret_cast<const float2*>(h + (cbase + e0.x) * 16 + sub * 2);
        ax += v0.x;
        ay += v0.y;
    }
    const float inv = 1.0f / fmaxf((float)(end - beg), 1.0f);
    float2 res;
    res.x = ax * inv;
    res.y = ay * inv;
    *reinterpret_cast<float2*>(mean + (cbase + d) * 16 + sub * 2) = res;
}

// ---------------- pooling (two-stage; batch sorted; node input chunked) ---------

__device__ int lower_bound_batch(const int* __restrict__ batch, int key) {
    int lo = 0, hi = N_NODES;
    while (lo < hi) {
        int mid = (lo + hi) >> 1;
        if (batch[mid] < key) lo = mid + 1;
        else hi = mid;
    }
    return lo;
}

__global__ void pool_partial(const float* __restrict__ node, const int* __restrict__ batch,
                             float* __restrict__ part) {
    const int b = blockIdx.x;          // g * SLICES + k
    const int g = b / SLICES;
    const int k = b % SLICES;
    const int t = threadIdx.x;         // feature t
    const long cbase = (long)(t >> 4) * N_NODES;
    const int foff = t & 15;
    const int lo = lower_bound_batch(batch, g);
    const int hi = lower_bound_batch(batch, g + 1);
    const int len = hi - lo;
    const int per = (len + SLICES - 1) / SLICES;
    const int s = lo + k * per;
    const int e = min(s + per, hi);
    float acc = 0.f;
    for (int i = s; i < e; i++) acc += node[(cbase + i) * 16 + foff];
    part[(long)b * HIDDEN + t] = acc;
}

__global__ void pool_reduce(const float* __restrict__ part, const int* __restrict__ batch,
                            float* __restrict__ out) {
    const int g = blockIdx.x;
    const int t = threadIdx.x;
    float acc = 0.f;
#pragma unroll
    for (int k = 0; k < SLICES; k++) acc += part[(long)(g * SLICES + k) * HIDDEN + t];
    const int lo = lower_bound_batch(batch, g);
    const int hi = lower_bound_batch(batch, g + 1);
    out[g * HIDDEN + t] = acc / fmaxf((float)(hi - lo), 1.0f);
}

// ---------------- launch ----------------

extern "C" void kernel_launch(void* const* d_in, const int* in_sizes, int n_in,
                              void* d_out, int out_size, void* d_ws, size_t ws_size,
                              hipStream_t stream) {
    const float* x    = (const float*)d_in[0];
    const int*   ei   = (const int*)d_in[1];   // [2][E]
    const int*   batch= (const int*)d_in[2];
    const float* W1   = (const float*)d_in[3];
    const float* b1   = (const float*)d_in[4];
    const float* W2   = (const float*)d_in[5];
    const float* b2   = (const float*)d_in[6];
    const float* W_l  = (const float*)d_in[7];
    const float* W_r  = (const float*)d_in[8];
    const float* b_s  = (const float*)d_in[9];
    float* out = (float*)d_out;

    const int* src = ei;
    const int* dst = ei + N_EDGES;

    // workspace layout
    char* ws = (char*)d_ws;
    const size_t NB = (size_t)N_NODES * HIDDEN * sizeof(float);  // 25.6 MB
    float* B1 = (float*)(ws);                    // h buffer (chunked)
    float* B2 = (float*)(ws + NB);               // mean buffer (chunked)
    float* B3 = (float*)(ws + 2 * NB);           // layer output (chunked)
    size_t off = 3 * NB;
    int*   deg      = (int*)(ws + off);   off += (size_t)N_NODES * 4;
    float* dinv     = (float*)(ws + off); off += (size_t)N_NODES * 4;
    int*   rowptr   = (int*)(ws + off);   off += (size_t)(N_NODES + 1) * 4;
    int*   fillcnt  = (int*)(ws + off);   off += (size_t)N_NODES * 4;
    int2*  csr      = (int2*)(ws + off);  off += (size_t)N_EDGES * 8;
    float* part     = (float*)(ws + off); off += (size_t)N_GRAPHS * SLICES * HIDDEN * 4;
    int*   bsum     = (int*)(ws + off);   off += (size_t)SCAN_B * 4;
    int*   boff     = (int*)(ws + off);   off += (size_t)SCAN_B * 4;

    const int EB = (N_EDGES + 255) / 256;
    const int GB = (N_NODES + 31) / 32;   // 32-row GEMM tiles
    const int WB = NG32 * 8;              // node-groups x chunks

    // ---- build CSR (once per call) ----
    hipMemsetAsync(deg, 0, (size_t)N_NODES * 4, stream);
    hipMemsetAsync(fillcnt, 0, (size_t)N_NODES * 4, stream);
    deg_kernel<<<EB, 256, 0, stream>>>(dst, deg);
    scan_partial<<<SCAN_B, 256, 0, stream>>>(deg, bsum);
    scan_bsum<<<1, 256, 0, stream>>>(bsum, boff, rowptr);
    scan_final<<<SCAN_B, 256, 0, stream>>>(deg, boff, rowptr, dinv);
    fill_kernel<<<EB, 256, 0, stream>>>(src, dst, rowptr, fillcnt, dinv, csr);

    // ---- GCN layer 1 ----
    gemm_kernel<false, false><<<GB, 256, 0, stream>>>(x, W1, B1, nullptr, N_NODES);
    gather_gcn<<<WB, 256, 0, stream>>>(B1, rowptr, csr, dinv, b1, B3);

    // ---- GCN layer 2 ----
    gemm_kernel<true, false><<<GB, 256, 0, stream>>>(B3, W2, B1, nullptr, N_NODES);
    gather_gcn<<<WB, 256, 0, stream>>>(B1, rowptr, csr, dinv, b2, B3);

    // ---- SAGE ----
    gather_sage<<<WB, 256, 0, stream>>>(B3, rowptr, csr, B2);
    gemm_sage<<<GB, 256, 0, stream>>>(B2, W_l, B3, W_r, b_s, B1, N_NODES);

    // ---- global mean pool (two-stage, no atomics) ----
    pool_partial<<<N_GRAPHS * SLICES, 128, 0, stream>>>(B1, batch, part);
    pool_reduce<<<N_GRAPHS, 128, 0, stream>>>(part, batch, out);
}

// Round 14
// 344.180 us; speedup vs baseline: 1.4416x; 1.2155x over previous
//
#include <hip/hip_runtime.h>

#define N_NODES 50000
#define N_EDGES 600000
#define HIDDEN 128
#define N_GRAPHS 64
#define SLICES 16
#define SCAN_B ((N_NODES + 255) / 256)   // 196
#define NG32 ((N_NODES + 31) / 32)       // 1563 node-groups of 32

typedef __attribute__((ext_vector_type(8))) short bf16x8;
typedef __attribute__((ext_vector_type(4))) float f32x4;

__device__ inline ushort f2bf(float v) {
    union { float f; unsigned u; } x; x.f = v;
    unsigned r = (x.u + 0x7FFF + ((x.u >> 16) & 1)) >> 16;  // RNE
    return (ushort)r;
}
__device__ inline float bf2f(ushort h) {
    union { unsigned u; float f; } x; x.u = ((unsigned)h) << 16;
    return x.f;
}

// Feature-chunked layout for node matrices: elem(n,f) at
// ((f>>4) * N_NODES + n) * 16 + (f & 15).  Chunk = 3.2 MB -> fits XCD L2.

// ---------------- degree ----------------

__global__ void deg_kernel(const int* __restrict__ dst, int* __restrict__ deg) {
    int t = blockIdx.x * 256 + threadIdx.x;
    if (t < N_EDGES) atomicAdd(&deg[dst[t]], 1);
}

// ---------------- 3-pass parallel scan: deg -> rowptr (+ fused dinv) ----------------

__global__ void scan_partial(const int* __restrict__ deg, int* __restrict__ bsum) {
    const int b = blockIdx.x, t = threadIdx.x;
    const int i = b * 256 + t;
    int v = (i < N_NODES) ? deg[i] : 0;
    __shared__ int wsum[4];
#pragma unroll
    for (int o = 32; o > 0; o >>= 1) v += __shfl_down(v, o, 64);
    if ((t & 63) == 0) wsum[t >> 6] = v;
    __syncthreads();
    if (t == 0) bsum[b] = wsum[0] + wsum[1] + wsum[2] + wsum[3];
}

__global__ void scan_bsum(const int* __restrict__ bsum, int* __restrict__ boff,
                          int* __restrict__ rowptr) {
    __shared__ int s[256];
    const int t = threadIdx.x;
    const int v = (t < SCAN_B) ? bsum[t] : 0;
    s[t] = v;
    __syncthreads();
    for (int o = 1; o < 256; o <<= 1) {
        int u = (t >= o) ? s[t - o] : 0;
        __syncthreads();
        s[t] += u;
        __syncthreads();
    }
    if (t < SCAN_B) boff[t] = s[t] - v;      // exclusive
    if (t == 255) rowptr[N_NODES] = s[255];  // total == N_EDGES
}

__global__ void scan_final(const int* __restrict__ deg, const int* __restrict__ boff,
                           int* __restrict__ rowptr, float* __restrict__ dinv) {
    const int b = blockIdx.x, t = threadIdx.x;
    const int i = b * 256 + t;
    __shared__ int s[256];
    const int v = (i < N_NODES) ? deg[i] : 0;
    s[t] = v;
    __syncthreads();
    for (int o = 1; o < 256; o <<= 1) {
        int u = (t >= o) ? s[t - o] : 0;
        __syncthreads();
        s[t] += u;
        __syncthreads();
    }
    if (i < N_NODES) {
        rowptr[i] = boff[b] + s[t] - v;
        dinv[i] = rsqrtf((float)v + 1.0f);
    }
}

// ---------------- CSR fill: interleaved {src, norm} ----------------

__global__ void fill_kernel(const int* __restrict__ src, const int* __restrict__ dst,
                            const int* __restrict__ rowptr, int* __restrict__ fillcnt,
                            const float* __restrict__ dinv, int2* __restrict__ csr) {
    int e = blockIdx.x * 256 + threadIdx.x;
    if (e >= N_EDGES) return;
    const int d = dst[e];
    const int s = src[e];
    const int pos = rowptr[d] + atomicAdd(&fillcnt[d], 1);
    csr[pos] = make_int2(s, __float_as_int(dinv[s] * dinv[d]));
}

// ---------------- W pack: fp32 [128k][128n] -> bf16 hi/lo in MFMA fragment order --
// frag element (s,c,lane,j) = W[s*32 + 8*(lane>>4) + j][c*16 + (lane&15)]
// packed at [m][ (s*8+c)*64*8 + lane*8 + j ]; hi at m*32768, lo at m*32768+16384.

__global__ void pack_w(const float* __restrict__ Wa, const float* __restrict__ Wb,
                       const float* __restrict__ Wc, const float* __restrict__ Wd,
                       ushort* __restrict__ out) {
    const int m = blockIdx.x >> 3;
    const int gid = (blockIdx.x & 7) * 256 + threadIdx.x;  // 0..2047
    const float* W = (m == 0) ? Wa : (m == 1) ? Wb : (m == 2) ? Wc : Wd;
    const int s = gid >> 9;
    const int c = (gid >> 6) & 7;
    const int lane = gid & 63;
    const int kbase = s * 32 + 8 * (lane >> 4);
    const int n = c * 16 + (lane & 15);
    ushort* hi = out + (long)m * 32768;
    ushort* lo = hi + 16384;
#pragma unroll
    for (int j = 0; j < 8; j++) {
        const float v = W[(kbase + j) * HIDDEN + n];
        const ushort h = f2bf(v);
        hi[gid * 8 + j] = h;
        lo[gid * 8 + j] = f2bf(v - bf2f(h));
    }
}

// ---------------- MFMA GEMM: C_chunked = A @ W ; 64-row tile, 256 thr, bf16x3 ----
// CHA: A feature-chunked; else row-major. C always chunked.
// LDS swizzle: full within-row byte offset XOR ((row&7)<<4), SAME on write & read.

template <bool CHA, bool BIAS>
__global__ void gemm_mfma(const float* __restrict__ A, const ushort* __restrict__ Wp,
                          float* __restrict__ C, const float* __restrict__ bias,
                          int nrows) {
    __shared__ alignas(16) ushort Ah[64 * 128];
    __shared__ alignas(16) ushort Al[64 * 128];
    const int r0 = blockIdx.x * 64;
    const int tid = threadIdx.x;

    // stage A -> bf16 hi/lo LDS, XOR-swizzled rows
#pragma unroll
    for (int i = 0; i < 8; i++) {
        const int idx = tid + i * 256;          // 0..2047 float4 slots
        const int node = idx >> 5;              // 0..63
        float4 v = make_float4(0.f, 0.f, 0.f, 0.f);
        int f0;
        if (CHA) {
            const int c = (idx >> 2) & 7;
            const int f4 = idx & 3;
            f0 = c * 16 + f4 * 4;
            if (r0 + node < nrows)
                v = reinterpret_cast<const float4*>(A)[((long)c * N_NODES + r0 + node) * 4 + f4];
        } else {
            f0 = 4 * (idx & 31);
            if (r0 + node < nrows)
                v = reinterpret_cast<const float4*>(A + (long)r0 * HIDDEN)[idx];
        }
        const ushort h0 = f2bf(v.x), h1 = f2bf(v.y), h2 = f2bf(v.z), h3 = f2bf(v.w);
        ushort4 h4; h4.x = h0; h4.y = h1; h4.z = h2; h4.w = h3;
        ushort4 l4;
        l4.x = f2bf(v.x - bf2f(h0)); l4.y = f2bf(v.y - bf2f(h1));
        l4.z = f2bf(v.z - bf2f(h2)); l4.w = f2bf(v.w - bf2f(h3));
        const int kb = (2 * f0) ^ ((node & 7) << 4);
        *reinterpret_cast<ushort4*>(&Ah[(node * 256 + kb) >> 1]) = h4;
        *reinterpret_cast<ushort4*>(&Al[(node * 256 + kb) >> 1]) = l4;
    }
    __syncthreads();

    const int wave = tid >> 6;
    const int lane = tid & 63;
    const int arow = 16 * wave + (lane & 15);

    f32x4 acc[8];
#pragma unroll
    for (int c = 0; c < 8; c++) acc[c] = (f32x4){0.f, 0.f, 0.f, 0.f};

#pragma unroll
    for (int s = 0; s < 4; s++) {
        // full-offset XOR: matches the write-side involution exactly
        const int koff = (s * 64 + ((lane >> 4) << 4)) ^ ((arow & 7) << 4);
        const bf16x8 ahi = *reinterpret_cast<const bf16x8*>(&Ah[(arow * 256 + koff) >> 1]);
        const bf16x8 alo = *reinterpret_cast<const bf16x8*>(&Al[(arow * 256 + koff) >> 1]);
#pragma unroll
        for (int c = 0; c < 8; c++) {
            const bf16x8 bhi = *reinterpret_cast<const bf16x8*>(&Wp[((s * 8 + c) * 64 + lane) * 8]);
            const bf16x8 blo = *reinterpret_cast<const bf16x8*>(&Wp[16384 + ((s * 8 + c) * 64 + lane) * 8]);
            acc[c] = __builtin_amdgcn_mfma_f32_16x16x32_bf16(ahi, bhi, acc[c], 0, 0, 0);
            acc[c] = __builtin_amdgcn_mfma_f32_16x16x32_bf16(alo, bhi, acc[c], 0, 0, 0);
            acc[c] = __builtin_amdgcn_mfma_f32_16x16x32_bf16(ahi, blo, acc[c], 0, 0, 0);
        }
    }

    const int node0 = r0 + 16 * wave + ((lane >> 4) << 2);
    const int fc = lane & 15;
#pragma unroll
    for (int c = 0; c < 8; c++) {
        const float bb = BIAS ? bias[c * 16 + fc] : 0.f;
#pragma unroll
        for (int reg = 0; reg < 4; reg++) {
            const int node = node0 + reg;
            if (node < nrows)
                C[((long)c * N_NODES + node) * 16 + fc] = acc[c][reg] + bb;
        }
    }
}

// ---------------- fused SAGE MFMA GEMM: C = A1@Wl + A2@Wr + b ----------------

__global__ void gemm_sage_mfma(const float* __restrict__ A1, const ushort* __restrict__ Wp1,
                               const float* __restrict__ A2, const ushort* __restrict__ Wp2,
                               const float* __restrict__ bias, float* __restrict__ C,
                               int nrows) {
    __shared__ alignas(16) ushort Ah[64 * 128];
    __shared__ alignas(16) ushort Al[64 * 128];
    const int r0 = blockIdx.x * 64;
    const int tid = threadIdx.x;
    const int wave = tid >> 6;
    const int lane = tid & 63;
    const int arow = 16 * wave + (lane & 15);

    f32x4 acc[8];
#pragma unroll
    for (int c = 0; c < 8; c++) acc[c] = (f32x4){0.f, 0.f, 0.f, 0.f};

    for (int p = 0; p < 2; p++) {
        const float* A = (p == 0) ? A1 : A2;
        const ushort* Wp = (p == 0) ? Wp1 : Wp2;
        if (p) __syncthreads();
#pragma unroll
        for (int i = 0; i < 8; i++) {
            const int idx = tid + i * 256;
            const int node = idx >> 5;
            const int c = (idx >> 2) & 7;
            const int f4 = idx & 3;
            const int f0 = c * 16 + f4 * 4;
            float4 v = make_float4(0.f, 0.f, 0.f, 0.f);
            if (r0 + node < nrows)
                v = reinterpret_cast<const float4*>(A)[((long)c * N_NODES + r0 + node) * 4 + f4];
            const ushort h0 = f2bf(v.x), h1 = f2bf(v.y), h2 = f2bf(v.z), h3 = f2bf(v.w);
            ushort4 h4; h4.x = h0; h4.y = h1; h4.z = h2; h4.w = h3;
            ushort4 l4;
            l4.x = f2bf(v.x - bf2f(h0)); l4.y = f2bf(v.y - bf2f(h1));
            l4.z = f2bf(v.z - bf2f(h2)); l4.w = f2bf(v.w - bf2f(h3));
            const int kb = (2 * f0) ^ ((node & 7) << 4);
            *reinterpret_cast<ushort4*>(&Ah[(node * 256 + kb) >> 1]) = h4;
            *reinterpret_cast<ushort4*>(&Al[(node * 256 + kb) >> 1]) = l4;
        }
        __syncthreads();

#pragma unroll
        for (int s = 0; s < 4; s++) {
            const int koff = (s * 64 + ((lane >> 4) << 4)) ^ ((arow & 7) << 4);
            const bf16x8 ahi = *reinterpret_cast<const bf16x8*>(&Ah[(arow * 256 + koff) >> 1]);
            const bf16x8 alo = *reinterpret_cast<const bf16x8*>(&Al[(arow * 256 + koff) >> 1]);
#pragma unroll
            for (int c = 0; c < 8; c++) {
                const bf16x8 bhi = *reinterpret_cast<const bf16x8*>(&Wp[((s * 8 + c) * 64 + lane) * 8]);
                const bf16x8 blo = *reinterpret_cast<const bf16x8*>(&Wp[16384 + ((s * 8 + c) * 64 + lane) * 8]);
                acc[c] = __builtin_amdgcn_mfma_f32_16x16x32_bf16(ahi, bhi, acc[c], 0, 0, 0);
                acc[c] = __builtin_amdgcn_mfma_f32_16x16x32_bf16(alo, bhi, acc[c], 0, 0, 0);
                acc[c] = __builtin_amdgcn_mfma_f32_16x16x32_bf16(ahi, blo, acc[c], 0, 0, 0);
            }
        }
    }

    const int node0 = r0 + 16 * wave + ((lane >> 4) << 2);
    const int fc = lane & 15;
#pragma unroll
    for (int c = 0; c < 8; c++) {
        const float bb = bias[c * 16 + fc];
#pragma unroll
        for (int reg = 0; reg < 4; reg++) {
            const int node = node0 + reg;
            if (node < nrows)
                C[((long)c * N_NODES + node) * 16 + fc] = acc[c][reg] + bb;
        }
    }
}

// ---------------- GCN gather (chunked): out = relu(sum h[s]*n + h[d]/deg + b) ----

__global__ void gather_gcn(const float* __restrict__ h, const int* __restrict__ rowptr,
                           const int2* __restrict__ csr, const float* __restrict__ dinv,
                           const float* __restrict__ bias, float* __restrict__ out) {
    const int tid = threadIdx.x;
    const int chunk = blockIdx.x & 7;
    const int ngrp = blockIdx.x >> 3;
    const int lane = tid & 63;
    const int nio = lane >> 3;
    const int sub = lane & 7;
    const int d = ngrp * 32 + (tid >> 6) * 8 + nio;
    if (d >= N_NODES) return;
    const float di = dinv[d];
    const int beg = rowptr[d];
    const int end = rowptr[d + 1];
    const long cbase = (long)chunk * N_NODES;
    float ax = 0.f, ay = 0.f;
    int j = beg;
    for (; j + 2 <= end; j += 2) {
        const int2 e0 = csr[j];
        const int2 e1 = csr[j + 1];
        const float n0 = __int_as_float(e0.y);
        const float n1 = __int_as_float(e1.y);
        const float2 v0 = *reinterpret_cast<const float2*>(h + (cbase + e0.x) * 16 + sub * 2);
        const float2 v1 = *reinterpret_cast<const float2*>(h + (cbase + e1.x) * 16 + sub * 2);
        ax += v0.x * n0 + v1.x * n1;
        ay += v0.y * n0 + v1.y * n1;
    }
    if (j < end) {
        const int2 e0 = csr[j];
        const float n0 = __int_as_float(e0.y);
        const float2 v0 = *reinterpret_cast<const float2*>(h + (cbase + e0.x) * 16 + sub * 2);
        ax += v0.x * n0;
        ay += v0.y * n0;
    }
    const float2 hv = *reinterpret_cast<const float2*>(h + (cbase + d) * 16 + sub * 2);
    const float2 b = *reinterpret_cast<const float2*>(bias + chunk * 16 + sub * 2);
    const float invdeg = di * di;
    float2 res;
    res.x = fmaxf(ax + hv.x * invdeg + b.x, 0.f);
    res.y = fmaxf(ay + hv.y * invdeg + b.y, 0.f);
    *reinterpret_cast<float2*>(out + (cbase + d) * 16 + sub * 2) = res;
}

// ---------------- SAGE mean gather (chunked) ----------------

__global__ void gather_sage(const float* __restrict__ h, const int* __restrict__ rowptr,
                            const int2* __restrict__ csr, float* __restrict__ mean) {
    const int tid = threadIdx.x;
    const int chunk = blockIdx.x & 7;
    const int ngrp = blockIdx.x >> 3;
    const int lane = tid & 63;
    const int nio = lane >> 3;
    const int sub = lane & 7;
    const int d = ngrp * 32 + (tid >> 6) * 8 + nio;
    if (d >= N_NODES) return;
    const int beg = rowptr[d];
    const int end = rowptr[d + 1];
    const long cbase = (long)chunk * N_NODES;
    float ax = 0.f, ay = 0.f;
    int j = beg;
    for (; j + 2 <= end; j += 2) {
        const int2 e0 = csr[j];
        const int2 e1 = csr[j + 1];
        const float2 v0 = *reinterpret_cast<const float2*>(h + (cbase + e0.x) * 16 + sub * 2);
        const float2 v1 = *reinterpret_cast<const float2*>(h + (cbase + e1.x) * 16 + sub * 2);
        ax += v0.x + v1.x;
        ay += v0.y + v1.y;
    }
    if (j < end) {
        const int2 e0 = csr[j];
        const float2 v0 = *reinterpret_cast<const float2*>(h + (cbase + e0.x) * 16 + sub * 2);
        ax += v0.x;
        ay += v0.y;
    }
    const float inv = 1.0f / fmaxf((float)(end - beg), 1.0f);
    float2 res;
    res.x = ax * inv;
    res.y = ay * inv;
    *reinterpret_cast<float2*>(mean + (cbase + d) * 16 + sub * 2) = res;
}

// ---------------- pooling (two-stage; batch sorted; node input chunked) ---------

__device__ int lower_bound_batch(const int* __restrict__ batch, int key) {
    int lo = 0, hi = N_NODES;
    while (lo < hi) {
        int mid = (lo + hi) >> 1;
        if (batch[mid] < key) lo = mid + 1;
        else hi = mid;
    }
    return lo;
}

__global__ void pool_partial(const float* __restrict__ node, const int* __restrict__ batch,
                             float* __restrict__ part) {
    const int b = blockIdx.x;          // g * SLICES + k
    const int g = b / SLICES;
    const int k = b % SLICES;
    const int t = threadIdx.x;         // feature t
    const long cbase = (long)(t >> 4) * N_NODES;
    const int foff = t & 15;
    const int lo = lower_bound_batch(batch, g);
    const int hi = lower_bound_batch(batch, g + 1);
    const int len = hi - lo;
    const int per = (len + SLICES - 1) / SLICES;
    const int s = lo + k * per;
    const int e = min(s + per, hi);
    float acc = 0.f;
    for (int i = s; i < e; i++) acc += node[(cbase + i) * 16 + foff];
    part[(long)b * HIDDEN + t] = acc;
}

__global__ void pool_reduce(const float* __restrict__ part, const int* __restrict__ batch,
                            float* __restrict__ out) {
    const int g = blockIdx.x;
    const int t = threadIdx.x;
    float acc = 0.f;
#pragma unroll
    for (int k = 0; k < SLICES; k++) acc += part[(long)(g * SLICES + k) * HIDDEN + t];
    const int lo = lower_bound_batch(batch, g);
    const int hi = lower_bound_batch(batch, g + 1);
    out[g * HIDDEN + t] = acc / fmaxf((float)(hi - lo), 1.0f);
}

// ---------------- launch ----------------

extern "C" void kernel_launch(void* const* d_in, const int* in_sizes, int n_in,
                              void* d_out, int out_size, void* d_ws, size_t ws_size,
                              hipStream_t stream) {
    const float* x    = (const float*)d_in[0];
    const int*   ei   = (const int*)d_in[1];   // [2][E]
    const int*   batch= (const int*)d_in[2];
    const float* W1   = (const float*)d_in[3];
    const float* b1   = (const float*)d_in[4];
    const float* W2   = (const float*)d_in[5];
    const float* b2   = (const float*)d_in[6];
    const float* W_l  = (const float*)d_in[7];
    const float* W_r  = (const float*)d_in[8];
    const float* b_s  = (const float*)d_in[9];
    float* out = (float*)d_out;

    const int* src = ei;
    const int* dst = ei + N_EDGES;

    // workspace layout
    char* ws = (char*)d_ws;
    const size_t NB = (size_t)N_NODES * HIDDEN * sizeof(float);  // 25.6 MB
    float* B1 = (float*)(ws);                    // h buffer (chunked)
    float* B2 = (float*)(ws + NB);               // mean buffer (chunked)
    float* B3 = (float*)(ws + 2 * NB);           // layer output (chunked)
    size_t off = 3 * NB;
    int*   deg      = (int*)(ws + off);   off += (size_t)N_NODES * 4;
    float* dinv     = (float*)(ws + off); off += (size_t)N_NODES * 4;
    int*   rowptr   = (int*)(ws + off);   off += (size_t)(N_NODES + 1) * 4;
    int*   fillcnt  = (int*)(ws + off);   off += (size_t)N_NODES * 4;
    int2*  csr      = (int2*)(ws + off);  off += (size_t)N_EDGES * 8;
    float* part     = (float*)(ws + off); off += (size_t)N_GRAPHS * SLICES * HIDDEN * 4;
    int*   bsum     = (int*)(ws + off);   off += (size_t)SCAN_B * 4;
    int*   boff     = (int*)(ws + off);   off += (size_t)SCAN_B * 4;
    ushort* wpack   = (ushort*)(ws + off); off += (size_t)4 * 32768 * 2;  // 4 x (hi16K+lo16K)

    const ushort* Wp1 = wpack;                // W1
    const ushort* Wp2 = wpack + 32768;        // W2
    const ushort* WpL = wpack + 2 * 32768;    // W_l
    const ushort* WpR = wpack + 3 * 32768;    // W_r

    const int EB = (N_EDGES + 255) / 256;
    const int GB = (N_NODES + 63) / 64;   // 64-row MFMA tiles (782)
    const int WB = NG32 * 8;              // node-groups x chunks

    // ---- pack weights (bf16 hi/lo, fragment order) ----
    pack_w<<<32, 256, 0, stream>>>(W1, W2, W_l, W_r, wpack);

    // ---- build CSR (once per call) ----
    hipMemsetAsync(deg, 0, (size_t)N_NODES * 4, stream);
    hipMemsetAsync(fillcnt, 0, (size_t)N_NODES * 4, stream);
    deg_kernel<<<EB, 256, 0, stream>>>(dst, deg);
    scan_partial<<<SCAN_B, 256, 0, stream>>>(deg, bsum);
    scan_bsum<<<1, 256, 0, stream>>>(bsum, boff, rowptr);
    scan_final<<<SCAN_B, 256, 0, stream>>>(deg, boff, rowptr, dinv);
    fill_kernel<<<EB, 256, 0, stream>>>(src, dst, rowptr, fillcnt, dinv, csr);

    // ---- GCN layer 1 ----
    gemm_mfma<false, false><<<GB, 256, 0, stream>>>(x, Wp1, B1, nullptr, N_NODES);
    gather_gcn<<<WB, 256, 0, stream>>>(B1, rowptr, csr, dinv, b1, B3);

    // ---- GCN layer 2 ----
    gemm_mfma<true, false><<<GB, 256, 0, stream>>>(B3, Wp2, B1, nullptr, N_NODES);
    gather_gcn<<<WB, 256, 0, stream>>>(B1, rowptr, csr, dinv, b2, B3);

    // ---- SAGE ----
    gather_sage<<<WB, 256, 0, stream>>>(B3, rowptr, csr, B2);
    gemm_sage_mfma<<<GB, 256, 0, stream>>>(B2, WpL, B3, WpR, b_s, B1, N_NODES);

    // ---- global mean pool (two-stage, no atomics) ----
    pool_partial<<<N_GRAPHS * SLICES, 128, 0, stream>>>(B1, batch, part);
    pool_reduce<<<N_GRAPHS, 128, 0, stream>>>(part, batch, out);
}